// Round 1
// baseline (381.297 us; speedup 1.0000x reference)
//
#include <hip/hip_runtime.h>

#define VOCAB 1024
#define CTX 8
#define DDIM 8192      // VOCAB * CTX
#define BATCH 1024

// ---------------------------------------------------------------------------
// Phase 1: one block per W-row d.
//   - Stage W[d, :] (32 KB) into LDS with coalesced float4 loads.
//   - Every thread computes 4 batch rows: sum of 8 LDS gathers + bias.
//   - Write outT[d, 0:1024] as contiguous float4 (4 KB per block).
// Reads: 256 MB of W (coalesced), x (32 KB, L1/L2-resident), b (1 scalar/blk).
// Writes: 32 MB, perfectly coalesced.
// ---------------------------------------------------------------------------
__global__ __launch_bounds__(256) void p1_gather(const int* __restrict__ x,
                                                 const float* __restrict__ W,
                                                 const float* __restrict__ b,
                                                 float* __restrict__ outT) {
    __shared__ float row[DDIM];  // 32 KB -> 5 blocks/CU
    const int d   = blockIdx.x;
    const int tid = threadIdx.x;
    const float* wrow = W + (size_t)d * DDIM;

    // 256 threads * float4 = 4 KB per iter; 8 iters for 32 KB.
#pragma unroll
    for (int it = 0; it < DDIM / (256 * 4); ++it) {
        const int e = (it * 256 + tid) * 4;
        const float4 v = *reinterpret_cast<const float4*>(wrow + e);
        *reinterpret_cast<float4*>(&row[e]) = v;
    }
    __syncthreads();

    const float bias = b[d];
    const int ibase = tid * 4;   // 4 consecutive batch rows per thread
    float4 res;
#pragma unroll
    for (int k = 0; k < 4; ++k) {
        const int i = ibase + k;
        const int4 xa = *reinterpret_cast<const int4*>(x + i * CTX);
        const int4 xb = *reinterpret_cast<const int4*>(x + i * CTX + 4);
        float s = row[0 * VOCAB + xa.x] + row[1 * VOCAB + xa.y] +
                  row[2 * VOCAB + xa.z] + row[3 * VOCAB + xa.w] +
                  row[4 * VOCAB + xb.x] + row[5 * VOCAB + xb.y] +
                  row[6 * VOCAB + xb.z] + row[7 * VOCAB + xb.w];
        (&res.x)[k] = s + bias;
    }
    *reinterpret_cast<float4*>(outT + (size_t)d * BATCH + ibase) = res;
}

// ---------------------------------------------------------------------------
// Phase 2: transpose outT [DDIM][BATCH] -> out [BATCH][DDIM].
// 64x64 f32 tiles, float4 on both global sides, padded LDS (2-way max = free).
// ---------------------------------------------------------------------------
__global__ __launch_bounds__(256) void p2_transpose(const float* __restrict__ outT,
                                                    float* __restrict__ out) {
    __shared__ float tile[64][65];           // [i_local][d_local], +1 pad
    const int i0  = (blockIdx.x & 15) * 64;  // 16 tiles over BATCH
    const int d0  = (blockIdx.x >> 4) * 64;  // 128 tiles over DDIM
    const int tid = threadIdx.x;
    const int c   = tid & 15;                // float4 column index
    const int r   = tid >> 4;                // row 0..15

#pragma unroll
    for (int p = 0; p < 4; ++p) {
        const int dl = r + p * 16;           // d_local
        const float4 v = *reinterpret_cast<const float4*>(
            outT + (size_t)(d0 + dl) * BATCH + i0 + c * 4);
        tile[c * 4 + 0][dl] = v.x;
        tile[c * 4 + 1][dl] = v.y;
        tile[c * 4 + 2][dl] = v.z;
        tile[c * 4 + 3][dl] = v.w;
    }
    __syncthreads();

#pragma unroll
    for (int p = 0; p < 4; ++p) {
        const int il = r + p * 16;           // i_local
        float4 v;
        v.x = tile[il][c * 4 + 0];
        v.y = tile[il][c * 4 + 1];
        v.z = tile[il][c * 4 + 2];
        v.w = tile[il][c * 4 + 3];
        *reinterpret_cast<float4*>(out + (size_t)(i0 + il) * DDIM + d0 + c * 4) = v;
    }
}

// ---------------------------------------------------------------------------
// Fallback (only if ws too small): direct gather, cache-reliant. Correct but
// slow; never expected to run on this harness.
// ---------------------------------------------------------------------------
__global__ __launch_bounds__(256) void fallback_direct(const int* __restrict__ x,
                                                       const float* __restrict__ W,
                                                       const float* __restrict__ b,
                                                       float* __restrict__ out) {
    const int i  = blockIdx.y;
    const int d0 = (blockIdx.x * 256 + threadIdx.x) * 4;
    if (d0 >= DDIM) return;
    int c[CTX];
#pragma unroll
    for (int t = 0; t < CTX; ++t) c[t] = t * VOCAB + x[i * CTX + t];
    float4 res;
#pragma unroll
    for (int j = 0; j < 4; ++j) {
        float s = b[d0 + j];
#pragma unroll
        for (int t = 0; t < CTX; ++t) s += W[(size_t)(d0 + j) * DDIM + c[t]];
        (&res.x)[j] = s;
    }
    *reinterpret_cast<float4*>(out + (size_t)i * DDIM + d0) = res;
}

extern "C" void kernel_launch(void* const* d_in, const int* in_sizes, int n_in,
                              void* d_out, int out_size, void* d_ws, size_t ws_size,
                              hipStream_t stream) {
    const int*   x = (const int*)d_in[0];
    const float* W = (const float*)d_in[1];
    const float* b = (const float*)d_in[2];
    float*     out = (float*)d_out;

    const size_t need = (size_t)DDIM * BATCH * sizeof(float);  // 32 MB
    if (ws_size >= need) {
        float* outT = (float*)d_ws;
        hipLaunchKernelGGL(p1_gather, dim3(DDIM), dim3(256), 0, stream,
                           x, W, b, outT);
        hipLaunchKernelGGL(p2_transpose, dim3(128 * 16), dim3(256), 0, stream,
                           outT, out);
    } else {
        hipLaunchKernelGGL(fallback_direct, dim3(DDIM / 1024, BATCH), dim3(256),
                           0, stream, x, W, b, out);
    }
}